// Round 1
// baseline (185.307 us; speedup 1.0000x reference)
//
#include <hip/hip_runtime.h>

// Problem: tensor [8192, 64, 64] fp32.
// Per batch b: (mx,my) = argmax location (first occurrence, row-major);
// loss = sum_b sum_{j,k} ((mx-j)^2 + (my-k)^2) * tensor[b,j,k]; output 1 float.

#define NB   8192   // batches
#define HW   4096   // 64*64 per batch
#define TPB  256    // threads per block
#define VPT  4      // float4 loads per thread -> 16 elements per thread

__global__ __launch_bounds__(TPB) void loss_main_kernel(
    const float* __restrict__ in, float* __restrict__ partial) {
    const int b = blockIdx.x;
    const int t = threadIdx.x;
    const int wave = t >> 6;
    const int lane = t & 63;

    const float4* base = (const float4*)(in + (size_t)b * HW);

    // Single global read: keep all 16 elements in registers.
    float4 v[VPT];
#pragma unroll
    for (int i = 0; i < VPT; ++i) {
        v[i] = base[i * TPB + t];
    }

    // ---- per-thread argmax (increasing idx order => strict '>' gives first occurrence) ----
    float best = -1.0f;
    int bidx = 0;
#pragma unroll
    for (int i = 0; i < VPT; ++i) {
        const int fi = (i * TPB + t) * 4;
        const float vals[4] = {v[i].x, v[i].y, v[i].z, v[i].w};
#pragma unroll
        for (int c = 0; c < 4; ++c) {
            if (vals[c] > best) { best = vals[c]; bidx = fi + c; }
        }
    }

    // ---- wave64 argmax reduction (tie-break: lower index wins) ----
#pragma unroll
    for (int off = 32; off > 0; off >>= 1) {
        float oval = __shfl_down(best, off, 64);
        int   oidx = __shfl_down(bidx, off, 64);
        if (oval > best || (oval == best && oidx < bidx)) { best = oval; bidx = oidx; }
    }

    // ---- cross-wave merge via LDS ----
    __shared__ float sval[4];
    __shared__ int   sidx[4];
    __shared__ int   smxy;  // packed (row<<6)|col of argmax
    if (lane == 0) { sval[wave] = best; sidx[wave] = bidx; }
    __syncthreads();
    if (t == 0) {
        float bb = sval[0]; int bi = sidx[0];
#pragma unroll
        for (int w = 1; w < 4; ++w) {
            if (sval[w] > bb || (sval[w] == bb && sidx[w] < bi)) { bb = sval[w]; bi = sidx[w]; }
        }
        smxy = bi;
    }
    __syncthreads();
    const float mx = (float)(smxy >> 6);
    const float my = (float)(smxy & 63);

    // ---- dist^2-weighted sum over the same registers (no second global read) ----
    float acc = 0.0f;
#pragma unroll
    for (int i = 0; i < VPT; ++i) {
        const int fi = (i * TPB + t) * 4;
        const float vals[4] = {v[i].x, v[i].y, v[i].z, v[i].w};
        // all 4 elements of a float4 share a row (fi aligned to 4, row width 64)
        const float dj = mx - (float)(fi >> 6);
        const float dj2 = dj * dj;
        const float kbase = (float)(fi & 63);
#pragma unroll
        for (int c = 0; c < 4; ++c) {
            const float dk = my - (kbase + (float)c);
            acc += (dj2 + dk * dk) * vals[c];
        }
    }

    // ---- block sum reduction ----
#pragma unroll
    for (int off = 32; off > 0; off >>= 1) acc += __shfl_down(acc, off, 64);
    __shared__ float ssum[4];
    if (lane == 0) ssum[wave] = acc;
    __syncthreads();
    if (t == 0) partial[b] = ssum[0] + ssum[1] + ssum[2] + ssum[3];
}

// Reduce 8192 per-block partials -> out[0]. Unconditionally overwrites d_out
// (handles the 0xAA re-poison before each timed launch).
__global__ __launch_bounds__(TPB) void loss_reduce_kernel(
    const float* __restrict__ partial, float* __restrict__ out) {
    const int t = threadIdx.x;
    float acc = 0.0f;
#pragma unroll
    for (int i = 0; i < NB / TPB; ++i) acc += partial[i * TPB + t];
#pragma unroll
    for (int off = 32; off > 0; off >>= 1) acc += __shfl_down(acc, off, 64);
    __shared__ float s[4];
    const int wave = t >> 6, lane = t & 63;
    if (lane == 0) s[wave] = acc;
    __syncthreads();
    if (t == 0) out[0] = s[0] + s[1] + s[2] + s[3];
}

extern "C" void kernel_launch(void* const* d_in, const int* in_sizes, int n_in,
                              void* d_out, int out_size, void* d_ws, size_t ws_size,
                              hipStream_t stream) {
    const float* in = (const float*)d_in[0];
    float* out = (float*)d_out;
    float* partial = (float*)d_ws;  // needs NB*4 = 32 KB

    loss_main_kernel<<<NB, TPB, 0, stream>>>(in, partial);
    loss_reduce_kernel<<<1, TPB, 0, stream>>>(partial, out);
}